// Round 6
// baseline (243.198 us; speedup 1.0000x reference)
//
#include <hip/hip_runtime.h>

#define N_NODES 50000
#define N_EDGES 800000
#define IN_F    128
#define HEADS   8
#define OUT_F   16

typedef unsigned short u16;
typedef __attribute__((ext_vector_type(8))) short bf16x8;   // 4 VGPRs
typedef __attribute__((ext_vector_type(4))) float f32x4;

__device__ __forceinline__ float bf2f(u16 u) {
    return __uint_as_float(((unsigned)u) << 16);
}
__device__ __forceinline__ u16 f2bf(float f) {
    unsigned u = __float_as_uint(f);
    unsigned r = 0x7fffu + ((u >> 16) & 1u);
    return (u16)((u + r) >> 16);
}
// dtype-adaptive float load: bf=true -> buffer is bf16, else fp32
__device__ __forceinline__ float ldf(const void* p, int i, bool bf) {
    return bf ? bf2f(((const u16*)p)[i]) : ((const float*)p)[i];
}

// ------------------------------------------------------------- dtype probe
__global__ void probe_dtype(const void* __restrict__ h, int* __restrict__ flag) {
    if (threadIdx.x == 0 && blockIdx.x == 0) {
        const u16* u = (const u16*)h;
        int cnt = 0;
        for (int i = 0; i < 128; ++i) {
            int e = (u[i] >> 7) & 0xFF;
            if (e >= 90 && e <= 141) cnt++;
        }
        *flag = (cnt >= 110) ? 1 : 0;
    }
}

// ------------------------------------------------- node projection (MFMA)
// ht2[n, f*8 + h] = head-interleaved projection (f=feat 0..15, h=head 0..7):
// the fused pass reads one bf16x8 (16B) per lane = 8 head-values of one
// feature; 16 lanes cover the whole 256B row coalesced.
// NOTE: no folded histogram here (v5 lesson: atomics-with-return before the
// __syncthreads stall every block on vmcnt(0) drain — tripled this kernel).
#define WT_STRIDE 136   // bf16 units; 272 B per row: 16B-aligned, banks spread
__global__ __launch_bounds__(256) void node_proj_mfma(
    const void* __restrict__ h, const void* __restrict__ Wn,
    const void* __restrict__ a_srcp, const void* __restrict__ a_dstp,
    const int* __restrict__ flag,
    u16* __restrict__ ht, float* __restrict__ s_src, float* __restrict__ s_dst)
{
    const bool bf = (*flag) != 0;
    __shared__ u16 Wsh[IN_F * WT_STRIDE];   // 34.8 KB, Wt[c][k]
    const int tid = threadIdx.x;

    // stage W transposed (coalesced read, scattered LDS write)
    for (int i = tid; i < IN_F * IN_F; i += 256) {
        int k = i >> 7, c = i & 127;
        u16 v = bf ? ((const u16*)Wn)[i] : f2bf(((const float*)Wn)[i]);
        Wsh[c * WT_STRIDE + k] = v;
    }
    __syncthreads();

    const int wave = tid >> 6, lane = tid & 63;
    const int m = lane & 15, q = lane >> 4;
    const int row_t = blockIdx.x * 64 + wave * 16;   // this wave's 16-row tile

    // A fragments for K=128 (4 chunks of 32)
    bf16x8 afr[4];
    int arow = row_t + m;
    if (arow >= N_NODES) arow = N_NODES - 1;         // clamp; writes guarded
    if (bf) {
        const u16* hp = (const u16*)h + (size_t)arow * IN_F;
        #pragma unroll
        for (int kt = 0; kt < 4; ++kt)
            afr[kt] = *(const bf16x8*)(hp + kt * 32 + q * 8);
    } else {
        const float* hp = (const float*)h + (size_t)arow * IN_F;
        #pragma unroll
        for (int kt = 0; kt < 4; ++kt) {
            bf16x8 t;
            #pragma unroll
            for (int j = 0; j < 8; ++j) t[j] = (short)f2bf(hp[kt * 32 + q * 8 + j]);
            afr[kt] = t;
        }
    }

    f32x4 accs[8];                                    // all 8 head tiles live
    #pragma unroll
    for (int ct = 0; ct < 8; ++ct) {                  // col tile == head
        f32x4 acc = {0.f, 0.f, 0.f, 0.f};
        #pragma unroll
        for (int kt = 0; kt < 4; ++kt) {
            bf16x8 bfr = *(const bf16x8*)(Wsh + (ct * 16 + m) * WT_STRIDE + kt * 32 + q * 8);
            acc = __builtin_amdgcn_mfma_f32_16x16x32_bf16(afr[kt], bfr, acc, 0, 0, 0);
        }
        accs[ct] = acc;
        const float asv = ldf(a_srcp, ct * 16 + m, bf);
        const float adv = ldf(a_dstp, ct * 16 + m, bf);
        float v1[4], v2[4];
        #pragma unroll
        for (int r = 0; r < 4; ++r) {
            v1[r] = acc[r] * asv;
            v2[r] = acc[r] * adv;
        }
        #pragma unroll
        for (int o = 1; o < 16; o <<= 1) {
            #pragma unroll
            for (int r = 0; r < 4; ++r) {
                v1[r] += __shfl_xor(v1[r], o, 16);
                v2[r] += __shfl_xor(v2[r], o, 16);
            }
        }
        if (m == 0) {
            #pragma unroll
            for (int r = 0; r < 4; ++r) {
                int grow = row_t + q * 4 + r;
                if (grow < N_NODES) {
                    s_src[grow * HEADS + ct] = v1[r];
                    s_dst[grow * HEADS + ct] = v2[r];
                }
            }
        }
    }

    // packed head-interleaved store: lane(m,q) owns ht2[row][m*8 + 0..7]
    #pragma unroll
    for (int r = 0; r < 4; ++r) {
        int grow = row_t + q * 4 + r;
        if (grow < N_NODES) {
            bf16x8 o;
            #pragma unroll
            for (int ct = 0; ct < 8; ++ct) o[ct] = (short)f2bf(accs[ct][r]);
            *(bf16x8*)(ht + (size_t)grow * IN_F + m * 8) = o;
        }
    }
}

// ------------------------------------------------- histogram + rank capture
// Standalone full-occupancy pass: the atomic RETURN is each edge's CSR slot,
// so the scatter pass needs no atomics at all.
__global__ __launch_bounds__(256) void hist_rank(const int* __restrict__ ei,
                                                 int* __restrict__ deg,
                                                 int* __restrict__ rank) {
    int e = blockIdx.x * 256 + threadIdx.x;
    if (e < N_EDGES) rank[e] = atomicAdd(&deg[ei[N_EDGES + e]], 1);
}

// -------------------------------------------------------- exclusive scan
// Single block, two-pass: thread t sums deg[t*52 .. t*52+52), one block scan
// of the 1024 thread-sums, then each thread writes its exclusive prefixes.
// Only 2 barriers; 400 KB of L2-hot traffic.
__global__ __launch_bounds__(1024) void scan_deg(const int* __restrict__ deg,
                                                 int* __restrict__ csr) {
    __shared__ int wsums[16];
    const int tid = threadIdx.x, lane = tid & 63, wid = tid >> 6;
    const int base = tid * 52;

    // pass 1: thread-local sum
    int s = 0;
    for (int c = 0; c < 13; ++c) {
        int idx = base + c * 4;
        if (idx + 3 < N_NODES) {
            int4 q = *(const int4*)(deg + idx);
            s += q.x + q.y + q.z + q.w;
        } else {
            for (int j = 0; j < 4; ++j)
                if (idx + j < N_NODES) s += deg[idx + j];
        }
    }

    // block scan of thread sums
    int x = s;
    #pragma unroll
    for (int o = 1; o < 64; o <<= 1) {
        int y = __shfl_up(x, o, 64);
        if (lane >= o) x += y;
    }
    if (lane == 63) wsums[wid] = x;
    __syncthreads();
    if (wid == 0) {
        int v = (lane < 16) ? wsums[lane] : 0;
        #pragma unroll
        for (int o = 1; o < 16; o <<= 1) {
            int y = __shfl_up(v, o, 16);
            if ((lane & 15) >= o) v += y;
        }
        if (lane < 16) wsums[lane] = v;
    }
    __syncthreads();
    int run = ((wid > 0) ? wsums[wid - 1] : 0) + (x - s);   // exclusive offset

    // pass 2: write exclusive prefixes (deg re-read from L2)
    for (int c = 0; c < 13; ++c) {
        int idx = base + c * 4;
        if (idx + 3 < N_NODES) {
            int4 q = *(const int4*)(deg + idx);
            int4 o4 = {run, run + q.x, run + q.x + q.y, run + q.x + q.y + q.z};
            *(int4*)(csr + idx) = o4;
            run += q.x + q.y + q.z + q.w;
        } else {
            for (int j = 0; j < 4; ++j)
                if (idx + j < N_NODES) { csr[idx + j] = run; run += deg[idx + j]; }
        }
    }
    if (tid == 1023) csr[N_NODES] = run;   // grand total
}

// ------------------------------------------------------------- scatter
// NO atomics: slot = csr[dst] + rank[e]. Payload = (src, efv bits) so the
// consumer never touches ef.
__global__ __launch_bounds__(256) void scatter_edges(
    const int* __restrict__ ei, const void* __restrict__ ef,
    const int* __restrict__ flag, const int* __restrict__ rank,
    const int* __restrict__ csr, int2* __restrict__ edges)
{
    const bool bf = (*flag) != 0;
    int e = blockIdx.x * 256 + threadIdx.x;
    if (e >= N_EDGES) return;
    int src = ei[e];
    int dst = ei[N_EDGES + e];
    int pos = csr[dst] + rank[e];
    float efv = ldf(ef, e, bf);
    edges[pos] = make_int2(src, __float_as_int(efv));
}

// --------------------------------------------------- fused aggregation
// One 16-lane group per dst node walks its CSR bucket: computes attn+exp
// inline (s_dst/We lane-local; edges[i] broadcast; s_src an L2/LLC-resident
// 32B gather), accumulates per-head numerators (lane = feature) and per-head
// exp-sums in registers, then normalizes, head-means, writes FINAL output.
// No atomics. ht gather hand-pipelined 1 deep.
// No max-shift: attn is statistically bounded (|a| < ~15 << 88), exp() safe.
__global__ __launch_bounds__(256) void fused_aggregate(
    const int* __restrict__ csr, const int2* __restrict__ edges,
    const void* __restrict__ We,
    const float* __restrict__ s_src, const float* __restrict__ s_dst,
    const u16* __restrict__ ht, const int* __restrict__ flag,
    void* __restrict__ out)
{
    const bool bf = (*flag) != 0;
    int g = blockIdx.x * 16 + (threadIdx.x >> 4);
    if (g >= N_NODES) return;
    int lane = threadIdx.x & 15, hh8 = lane & 7;
    int beg = csr[g], end = csr[g + 1];
    float dval = s_dst[g * HEADS + hh8];
    float wev = ldf(We, hh8, bf);

    float num[8] = {0.f, 0.f, 0.f, 0.f, 0.f, 0.f, 0.f, 0.f};
    float ssum = 0.f;

    int i = beg;
    float svN = 0.f, efN = 0.f;
    bf16x8 vN = {0, 0, 0, 0, 0, 0, 0, 0};
    if (i < end) {
        int2 e0 = edges[i];
        svN = s_src[e0.x * HEADS + hh8];
        efN = __int_as_float(e0.y);
        vN = *(const bf16x8*)(ht + (size_t)e0.x * IN_F + lane * 8);
    }
    for (; i < end; ++i) {
        float sv = svN, efv = efN;
        bf16x8 vC = vN;
        if (i + 1 < end) {                  // prefetch next edge
            int2 e1 = edges[i + 1];
            svN = s_src[e1.x * HEADS + hh8];
            efN = __int_as_float(e1.y);
            vN = *(const bf16x8*)(ht + (size_t)e1.x * IN_F + lane * 8);
        }
        float a = sv + dval + efv * wev;
        a = (a > 0.f) ? a : 0.2f * a;       // leaky_relu 0.2
        float ex = __expf(a);
        ssum += ex;                          // head hh8 (halves duplicate)
        #pragma unroll
        for (int hh = 0; hh < 8; ++hh) {
            float ah = __shfl(ex, hh, 16);
            num[hh] = fmaf(ah, bf2f((u16)vC[hh]), num[hh]);
        }
    }

    float o = 0.f;
    #pragma unroll
    for (int hh = 0; hh < 8; ++hh) {
        float sh = __shfl(ssum, hh, 16);
        o += num[hh] / fmaxf(sh, 1e-12f);
    }
    o *= 0.125f;                             // head mean
    if (bf) ((u16*)out)[(size_t)g * OUT_F + lane] = f2bf(o);
    else    ((float*)out)[(size_t)g * OUT_F + lane] = o;
}

// ---------------------------------------------------------------- launch
extern "C" void kernel_launch(void* const* d_in, const int* in_sizes, int n_in,
                              void* d_out, int out_size, void* d_ws, size_t ws_size,
                              hipStream_t stream) {
    const void* h     = d_in[0];
    const int*  ei    = (const int*)d_in[1];
    const void* efeat = d_in[2];
    const void* Wn    = d_in[3];
    const void* We    = d_in[4];
    const void* a_src = d_in[5];
    const void* a_dst = d_in[6];

    char* ws = (char*)d_ws;
    int*   flag    = (int*)ws;   ws += 256;
    u16*   ht      = (u16*)ws;   ws += (size_t)N_NODES * IN_F * 2;     // 12.8 MB
    float* s_src   = (float*)ws; ws += (size_t)N_NODES * HEADS * 4;    // 1.6 MB
    float* s_dst   = (float*)ws; ws += (size_t)N_NODES * HEADS * 4;    // 1.6 MB
    int*   deg     = (int*)ws;   ws += (size_t)50048 * 4;              // padded
    int*   csr     = (int*)ws;   ws += (size_t)50048 * 4;              // N+1 used
    int*   rank    = (int*)ws;   ws += (size_t)N_EDGES * 4;            // 3.2 MB
    int2*  edges   = (int2*)ws;  ws += (size_t)N_EDGES * 8;            // 6.4 MB

    hipLaunchKernelGGL(probe_dtype, dim3(1), dim3(64), 0, stream, h, flag);
    hipMemsetAsync(deg, 0, (size_t)N_NODES * 4, stream);
    hipLaunchKernelGGL(node_proj_mfma, dim3((N_NODES + 63) / 64), dim3(256),
                       0, stream, h, Wn, a_src, a_dst, flag, ht, s_src, s_dst);
    hipLaunchKernelGGL(hist_rank, dim3((N_EDGES + 255) / 256), dim3(256),
                       0, stream, ei, deg, rank);
    hipLaunchKernelGGL(scan_deg, dim3(1), dim3(1024), 0, stream, deg, csr);
    hipLaunchKernelGGL(scatter_edges, dim3((N_EDGES + 255) / 256), dim3(256),
                       0, stream, ei, efeat, flag, rank, csr, edges);
    hipLaunchKernelGGL(fused_aggregate, dim3((N_NODES + 15) / 16), dim3(256),
                       0, stream, csr, edges, We, s_src, s_dst, ht, flag, d_out);
}

// Round 7
// 213.109 us; speedup vs baseline: 1.1412x; 1.1412x over previous
//
#include <hip/hip_runtime.h>

#define N_NODES 50000
#define N_EDGES 800000
#define IN_F    128
#define HEADS   8
#define OUT_F   16
#define NB_PROJ 782           // ceil(50000/64)
#define NB_HIST 3125          // 800000/256

typedef unsigned short u16;
typedef __attribute__((ext_vector_type(8))) short bf16x8;   // 4 VGPRs
typedef __attribute__((ext_vector_type(4))) float f32x4;

__device__ __forceinline__ float bf2f(u16 u) {
    return __uint_as_float(((unsigned)u) << 16);
}
__device__ __forceinline__ u16 f2bf(float f) {
    unsigned u = __float_as_uint(f);
    unsigned r = 0x7fffu + ((u >> 16) & 1u);
    return (u16)((u + r) >> 16);
}
// dtype-adaptive float load: bf=true -> buffer is bf16, else fp32
__device__ __forceinline__ float ldf(const void* p, int i, bool bf) {
    return bf ? bf2f(((const u16*)p)[i]) : ((const float*)p)[i];
}

// ------------------------------------------------------------- dtype probe
__global__ void probe_dtype(const void* __restrict__ h, int* __restrict__ flag) {
    if (threadIdx.x == 0 && blockIdx.x == 0) {
        const u16* u = (const u16*)h;
        int cnt = 0;
        for (int i = 0; i < 128; ++i) {
            int e = (u[i] >> 7) & 0xFF;
            if (e >= 90 && e <= 141) cnt++;
        }
        *flag = (cnt >= 110) ? 1 : 0;
    }
}

// --------------------------- node projection (MFMA) + overlapped histogram
// Blocks [0, NB_PROJ): projection. Blocks [NB_PROJ, NB_PROJ+NB_HIST): the
// 800k-atomic histogram (rank capture) -- SEPARATE blocks so the RMW latency
// overlaps proj instead of stalling its barrier (v5 lesson).
//
// Projection:
//  - W staged transposed with vectorized loads (1KB/wave-instr) and a
//    k-block XOR swizzle (bank spread on both write and read).
//  - ht stored HEAD-MAJOR [n][h*16+f] via a wave-local LDS transpose of the
//    MFMA accumulators (reusing Wsh after a barrier): coalesced 16B stores.
//  - s_src/s_dst computed from the same LDS rows with f32 a-tables
//    (replaces the 256-swizzle shuffle epilogue).
#define WT_STRIDE 136   // u16 units; 272 B per row
__global__ __launch_bounds__(256) void proj_hist(
    const void* __restrict__ h, const void* __restrict__ Wn,
    const void* __restrict__ a_srcp, const void* __restrict__ a_dstp,
    const int* __restrict__ flag, const int* __restrict__ ei,
    u16* __restrict__ ht, float* __restrict__ s_src, float* __restrict__ s_dst,
    int* __restrict__ deg, int* __restrict__ rank)
{
    if (blockIdx.x >= NB_PROJ) {            // ---------------- histogram part
        int e = (blockIdx.x - NB_PROJ) * 256 + threadIdx.x;
        if (e < N_EDGES) rank[e] = atomicAdd(&deg[ei[N_EDGES + e]], 1);
        return;
    }

    const bool bf = (*flag) != 0;
    __shared__ u16 Wsh[IN_F * WT_STRIDE];   // 34.8 KB, Wt[c][k] (k swizzled)
    __shared__ float a_sh[2][IN_F];         // f32 a_src / a_dst
    const int tid = threadIdx.x;

    if (tid < 128) a_sh[0][tid] = ldf(a_srcp, tid, bf);
    else           a_sh[1][tid - 128] = ldf(a_dstp, tid - 128, bf);

    // ---- stage W transposed, vectorized + swizzled
    {
        const int c8  = (tid & 15) * 8;     // 8-col chunk base
        const int kof = tid >> 4;           // row offset 0..15
        const int ksw = (tid & 7) << 3;     // k-swizzle for these cols
        bf16x8 wv[8];
        if (bf) {
            const u16* wp = (const u16*)Wn;
            #pragma unroll
            for (int j = 0; j < 8; ++j)     // 1KB contiguous per wave instr
                wv[j] = *(const bf16x8*)(wp + (size_t)(j * 16 + kof) * IN_F + c8);
        } else {
            const float* wp = (const float*)Wn;
            #pragma unroll
            for (int j = 0; j < 8; ++j) {
                const float* rp = wp + (size_t)(j * 16 + kof) * IN_F + c8;
                float4 fa = *(const float4*)(rp);
                float4 fb = *(const float4*)(rp + 4);
                bf16x8 t;
                t[0] = (short)f2bf(fa.x); t[1] = (short)f2bf(fa.y);
                t[2] = (short)f2bf(fa.z); t[3] = (short)f2bf(fa.w);
                t[4] = (short)f2bf(fb.x); t[5] = (short)f2bf(fb.y);
                t[6] = (short)f2bf(fb.z); t[7] = (short)f2bf(fb.w);
                wv[j] = t;
            }
        }
        #pragma unroll
        for (int j = 0; j < 8; ++j) {
            int kk = (j * 16 + kof) ^ ksw;
            #pragma unroll
            for (int jj = 0; jj < 8; ++jj)
                Wsh[(c8 + jj) * WT_STRIDE + kk] = (u16)wv[j][jj];
        }
    }
    __syncthreads();

    const int wave = tid >> 6, lane = tid & 63;
    const int m = lane & 15, q = lane >> 4;
    const int row_t = blockIdx.x * 64 + wave * 16;   // this wave's 16-row tile

    // A fragments for K=128 (4 chunks of 32)
    bf16x8 afr[4];
    int arow = row_t + m;
    if (arow >= N_NODES) arow = N_NODES - 1;         // clamp; writes guarded
    if (bf) {
        const u16* hp = (const u16*)h + (size_t)arow * IN_F;
        #pragma unroll
        for (int kt = 0; kt < 4; ++kt)
            afr[kt] = *(const bf16x8*)(hp + kt * 32 + q * 8);
    } else {
        const float* hp = (const float*)h + (size_t)arow * IN_F;
        #pragma unroll
        for (int kt = 0; kt < 4; ++kt) {
            bf16x8 t;
            #pragma unroll
            for (int j = 0; j < 8; ++j) t[j] = (short)f2bf(hp[kt * 32 + q * 8 + j]);
            afr[kt] = t;
        }
    }

    f32x4 accs[8];
    #pragma unroll
    for (int ct = 0; ct < 8; ++ct) {                 // col tile == head
        const int csw = ((2 * ct + (m >> 3)) & 7) << 3;   // read-side swizzle
        f32x4 acc = {0.f, 0.f, 0.f, 0.f};
        #pragma unroll
        for (int kt = 0; kt < 4; ++kt) {
            bf16x8 bfr = *(const bf16x8*)(Wsh + (ct * 16 + m) * WT_STRIDE
                                          + ((kt * 32 + q * 8) ^ csw));
            acc = __builtin_amdgcn_mfma_f32_16x16x32_bf16(afr[kt], bfr, acc, 0, 0, 0);
        }
        accs[ct] = acc;
    }

    __syncthreads();    // all waves done reading Wsh -> reuse as scratch

    // wave-local transpose: rows [wave*16, wave*16+16) of Wsh, [row][c] bf16
    const int wbase = wave * 16;
    #pragma unroll
    for (int ct = 0; ct < 8; ++ct)
        #pragma unroll
        for (int r = 0; r < 4; ++r)
            Wsh[(wbase + q * 4 + r) * WT_STRIDE + ct * 16 + m] = f2bf(accs[ct][r]);

    // read back: lane covers row r2 = lane&15, channel chunk hp = lane>>4
    const int r2 = lane & 15, hp2 = lane >> 4;
    const int grow = row_t + r2;
    const u16* wrow = Wsh + (wbase + r2) * WT_STRIDE;
    bf16x8 h0 = *(const bf16x8*)(wrow + hp2 * 32);
    bf16x8 h1 = *(const bf16x8*)(wrow + hp2 * 32 + 8);
    bf16x8 h2 = *(const bf16x8*)(wrow + hp2 * 32 + 16);
    bf16x8 h3 = *(const bf16x8*)(wrow + hp2 * 32 + 24);

    if (grow < N_NODES) {
        u16* hb = ht + (size_t)grow * IN_F + hp2 * 32;
        *(bf16x8*)(hb)      = h0;
        *(bf16x8*)(hb + 8)  = h1;
        *(bf16x8*)(hb + 16) = h2;
        *(bf16x8*)(hb + 24) = h3;
    }

    // s-dots: chunk hp2*32 = heads 2*hp2 (h0,h1) and 2*hp2+1 (h2,h3)
    #pragma unroll
    for (int hh = 0; hh < 2; ++hh) {
        const int hd = hp2 * 2 + hh;
        float s1 = 0.f, s2 = 0.f;
        #pragma unroll
        for (int f = 0; f < 8; ++f) {
            float xa = bf2f((u16)((hh == 0) ? h0[f] : h2[f]));
            float xb = bf2f((u16)((hh == 0) ? h1[f] : h3[f]));
            s1 = fmaf(xa, a_sh[0][hd * 16 + f], s1);
            s1 = fmaf(xb, a_sh[0][hd * 16 + 8 + f], s1);
            s2 = fmaf(xa, a_sh[1][hd * 16 + f], s2);
            s2 = fmaf(xb, a_sh[1][hd * 16 + 8 + f], s2);
        }
        if (grow < N_NODES) {
            s_src[grow * HEADS + hd] = s1;
            s_dst[grow * HEADS + hd] = s2;
        }
    }
}

// -------------------------------------------------------- exclusive scan
// Single block, two-pass: thread t sums deg[t*52 .. t*52+52), one block scan
// of the 1024 thread-sums, then each thread writes its exclusive prefixes.
__global__ __launch_bounds__(1024) void scan_deg(const int* __restrict__ deg,
                                                 int* __restrict__ csr) {
    __shared__ int wsums[16];
    const int tid = threadIdx.x, lane = tid & 63, wid = tid >> 6;
    const int base = tid * 52;

    int s = 0;
    for (int c = 0; c < 13; ++c) {
        int idx = base + c * 4;
        if (idx + 3 < N_NODES) {
            int4 q = *(const int4*)(deg + idx);
            s += q.x + q.y + q.z + q.w;
        } else {
            for (int j = 0; j < 4; ++j)
                if (idx + j < N_NODES) s += deg[idx + j];
        }
    }

    int x = s;
    #pragma unroll
    for (int o = 1; o < 64; o <<= 1) {
        int y = __shfl_up(x, o, 64);
        if (lane >= o) x += y;
    }
    if (lane == 63) wsums[wid] = x;
    __syncthreads();
    if (wid == 0) {
        int v = (lane < 16) ? wsums[lane] : 0;
        #pragma unroll
        for (int o = 1; o < 16; o <<= 1) {
            int y = __shfl_up(v, o, 16);
            if ((lane & 15) >= o) v += y;
        }
        if (lane < 16) wsums[lane] = v;
    }
    __syncthreads();
    int run = ((wid > 0) ? wsums[wid - 1] : 0) + (x - s);

    for (int c = 0; c < 13; ++c) {
        int idx = base + c * 4;
        if (idx + 3 < N_NODES) {
            int4 q = *(const int4*)(deg + idx);
            int4 o4 = {run, run + q.x, run + q.x + q.y, run + q.x + q.y + q.z};
            *(int4*)(csr + idx) = o4;
            run += q.x + q.y + q.z + q.w;
        } else {
            for (int j = 0; j < 4; ++j)
                if (idx + j < N_NODES) { csr[idx + j] = run; run += deg[idx + j]; }
        }
    }
    if (tid == 1023) csr[N_NODES] = run;
}

// ------------------------------------------------------------- scatter
// NO atomics: slot = csr[dst] + rank[e]. Payload = (src, efv bits).
__global__ __launch_bounds__(256) void scatter_edges(
    const int* __restrict__ ei, const void* __restrict__ ef,
    const int* __restrict__ flag, const int* __restrict__ rank,
    const int* __restrict__ csr, int2* __restrict__ edges)
{
    const bool bf = (*flag) != 0;
    int e = blockIdx.x * 256 + threadIdx.x;
    if (e >= N_EDGES) return;
    int src = ei[e];
    int dst = ei[N_EDGES + e];
    int pos = csr[dst] + rank[e];
    float efv = ldf(ef, e, bf);
    edges[pos] = make_int2(src, __float_as_int(efv));
}

// --------------------------------------------------- fused aggregation
// 8 lanes per dst node, lane = head. Each lane computes its head's exp and
// accumulates num[f] for its head's 16 features from a 2x16B read (8 lanes
// cover the 256B head-major ht row coalesced). ZERO shuffles per edge; one
// 48-shuffle head-reduce per node at the end. No atomics.
// No max-shift: attn is statistically bounded (|a| < ~15 << 88), exp() safe.
__global__ __launch_bounds__(256) void fused_aggregate(
    const int* __restrict__ csr, const int2* __restrict__ edges,
    const void* __restrict__ We,
    const float* __restrict__ s_src, const float* __restrict__ s_dst,
    const u16* __restrict__ ht, const int* __restrict__ flag,
    void* __restrict__ out)
{
    const bool bf = (*flag) != 0;
    int g = blockIdx.x * 32 + (threadIdx.x >> 3);
    if (g >= N_NODES) return;
    const int hd = threadIdx.x & 7;
    int beg = csr[g], end = csr[g + 1];
    const float dval = s_dst[g * HEADS + hd];
    const float wev = ldf(We, hd, bf);

    float num[16];
    #pragma unroll
    for (int f = 0; f < 16; ++f) num[f] = 0.f;
    float den = 0.f;

    int2 eN = make_int2(0, 0);
    float svN = 0.f;
    bf16x8 v0N = {0,0,0,0,0,0,0,0}, v1N = {0,0,0,0,0,0,0,0};
    if (beg < end) {
        eN = edges[beg];
        svN = s_src[eN.x * HEADS + hd];
        const u16* hp = ht + (size_t)eN.x * IN_F + hd * 16;
        v0N = *(const bf16x8*)hp;
        v1N = *(const bf16x8*)(hp + 8);
    }
    for (int i = beg; i < end; ++i) {
        int2 eC = eN;
        float sv = svN;
        bf16x8 v0 = v0N, v1 = v1N;
        if (i + 1 < end) {                   // prefetch next edge
            eN = edges[i + 1];
            svN = s_src[eN.x * HEADS + hd];
            const u16* hp = ht + (size_t)eN.x * IN_F + hd * 16;
            v0N = *(const bf16x8*)hp;
            v1N = *(const bf16x8*)(hp + 8);
        }
        float a = sv + dval + __int_as_float(eC.y) * wev;
        a = (a > 0.f) ? a : 0.2f * a;        // leaky_relu 0.2
        float ex = __expf(a);
        den += ex;
        #pragma unroll
        for (int f = 0; f < 8; ++f) {
            num[f]     = fmaf(ex, bf2f((u16)v0[f]), num[f]);
            num[8 + f] = fmaf(ex, bf2f((u16)v1[f]), num[8 + f]);
        }
    }

    float rc = 1.0f / fmaxf(den, 1e-12f);    // per-head normalizer
    #pragma unroll
    for (int f = 0; f < 16; ++f) num[f] *= rc;
    #pragma unroll
    for (int o = 1; o < 8; o <<= 1)          // sum across the 8 head-lanes
        #pragma unroll
        for (int f = 0; f < 16; ++f)
            num[f] += __shfl_xor(num[f], o, 8);

    float o0 = num[2 * hd] * 0.125f;
    float o1 = num[2 * hd + 1] * 0.125f;
    if (bf) {
        unsigned pw = ((unsigned)f2bf(o1) << 16) | (unsigned)f2bf(o0);
        *(unsigned*)((u16*)out + (size_t)g * OUT_F + hd * 2) = pw;
    } else {
        float2 f2v = {o0, o1};
        *(float2*)((float*)out + (size_t)g * OUT_F + hd * 2) = f2v;
    }
}

// ---------------------------------------------------------------- launch
extern "C" void kernel_launch(void* const* d_in, const int* in_sizes, int n_in,
                              void* d_out, int out_size, void* d_ws, size_t ws_size,
                              hipStream_t stream) {
    const void* h     = d_in[0];
    const int*  ei    = (const int*)d_in[1];
    const void* efeat = d_in[2];
    const void* Wn    = d_in[3];
    const void* We    = d_in[4];
    const void* a_src = d_in[5];
    const void* a_dst = d_in[6];

    char* ws = (char*)d_ws;
    int*   flag    = (int*)ws;   ws += 256;
    u16*   ht      = (u16*)ws;   ws += (size_t)N_NODES * IN_F * 2;     // 12.8 MB
    float* s_src   = (float*)ws; ws += (size_t)N_NODES * HEADS * 4;    // 1.6 MB
    float* s_dst   = (float*)ws; ws += (size_t)N_NODES * HEADS * 4;    // 1.6 MB
    int*   deg     = (int*)ws;   ws += (size_t)50048 * 4;              // padded
    int*   csr     = (int*)ws;   ws += (size_t)50048 * 4;              // N+1 used
    int*   rank    = (int*)ws;   ws += (size_t)N_EDGES * 4;            // 3.2 MB
    int2*  edges   = (int2*)ws;  ws += (size_t)N_EDGES * 8;            // 6.4 MB

    hipLaunchKernelGGL(probe_dtype, dim3(1), dim3(64), 0, stream, h, flag);
    hipMemsetAsync(deg, 0, (size_t)N_NODES * 4, stream);
    hipLaunchKernelGGL(proj_hist, dim3(NB_PROJ + NB_HIST), dim3(256),
                       0, stream, h, Wn, a_src, a_dst, flag, ei,
                       ht, s_src, s_dst, deg, rank);
    hipLaunchKernelGGL(scan_deg, dim3(1), dim3(1024), 0, stream, deg, csr);
    hipLaunchKernelGGL(scatter_edges, dim3((N_EDGES + 255) / 256), dim3(256),
                       0, stream, ei, efeat, flag, rank, csr, edges);
    hipLaunchKernelGGL(fused_aggregate, dim3((N_NODES + 31) / 32), dim3(256),
                       0, stream, csr, edges, We, s_src, s_dst, ht, flag, d_out);
}